// Round 7
// baseline (415.858 us; speedup 1.0000x reference)
//
#include <hip/hip_runtime.h>
#include <math.h>

#define NEG_SLOPE 0.2f
#define CAP 128   // max in-edges/node in LDS; deg~Binom(640K,1/20K) mean 32 → ample

typedef short s16x8 __attribute__((ext_vector_type(8)));
typedef unsigned short us8 __attribute__((ext_vector_type(8)));
typedef float f32x4 __attribute__((ext_vector_type(4)));

__device__ __forceinline__ unsigned short f2bf(float f) {
    unsigned int u = __float_as_uint(f);
    return (unsigned short)((u + 0x7FFFu + ((u >> 16) & 1u)) >> 16);
}
__device__ __forceinline__ float bf2f(unsigned short s) {
    return __uint_as_float(((unsigned int)s) << 16);
}

// ==================== prep: x->bf16, W1/W2 transpose->bf16, deg=0, ce1/ce2 ====================
__global__ __launch_bounds__(256) void prep_kernel(const float* __restrict__ x,
                                                   const float* __restrict__ W1,
                                                   const float* __restrict__ W2,
                                                   const float* __restrict__ W_e1,
                                                   const float* __restrict__ a_e1,
                                                   const float* __restrict__ W_e2,
                                                   const float* __restrict__ a_e2,
                                                   unsigned short* __restrict__ x16,
                                                   unsigned short* __restrict__ Wt1,
                                                   unsigned short* __restrict__ Wt2,
                                                   int* __restrict__ deg,
                                                   float* __restrict__ ce,  // [8]: ce1, ce2
                                                   int N) {
    const int gsz = gridDim.x * blockDim.x;
    int gid = blockIdx.x * blockDim.x + threadIdx.x;
    for (int i = gid; i < N * 128; i += gsz) x16[i] = f2bf(x[i]);
    for (int i = gid; i < 128 * 256; i += gsz) {
        int k = i >> 8, n = i & 255;
        Wt1[n * 128 + k] = f2bf(W1[i]);
    }
    for (int i = gid; i < 256 * 256; i += gsz) {
        int k = i >> 8, n = i & 255;
        Wt2[n * 256 + k] = f2bf(W2[i]);
    }
    for (int i = gid; i < N; i += gsz) deg[i] = 0;
    if (blockIdx.x < 2) {
        const float* We = blockIdx.x == 0 ? W_e1 : W_e2;
        const float* ae = blockIdx.x == 0 ? a_e1 : a_e2;
        int h = threadIdx.x >> 6, c = threadIdx.x & 63;
        float p = We[h * 64 + c] * ae[h * 64 + c];
#pragma unroll
        for (int off = 32; off > 0; off >>= 1) p += __shfl_down(p, off);
        if (c == 0) ce[blockIdx.x * 4 + h] = p;
    }
}

// ==================== CSR build ====================
__global__ __launch_bounds__(256) void hist_kernel(const int* __restrict__ dst,
                                                   int* __restrict__ deg, int E) {
    int e = blockIdx.x * blockDim.x + threadIdx.x;
    if (e < E) atomicAdd(&deg[dst[e]], 1);
}

__global__ __launch_bounds__(1024) void scan_kernel(const int* __restrict__ deg,
                                                    int* __restrict__ off,
                                                    int* __restrict__ cursor, int N) {
    __shared__ int wsum[16];
    __shared__ int woff[16];
    __shared__ int s_carry, s_bt;
    if (threadIdx.x == 0) s_carry = 0;
    __syncthreads();
    const int lane = threadIdx.x & 63, wid = threadIdx.x >> 6;
    for (int base = 0; base < N; base += 1024) {
        int i = base + (int)threadIdx.x;
        int v = (i < N) ? deg[i] : 0;
        int incl = v;
#pragma unroll
        for (int ofs = 1; ofs < 64; ofs <<= 1) {
            int t = __shfl_up(incl, ofs);
            if (lane >= ofs) incl += t;
        }
        if (lane == 63) wsum[wid] = incl;
        __syncthreads();
        if (wid == 0) {
            int ws = (lane < 16) ? wsum[lane] : 0;
            int wincl = ws;
#pragma unroll
            for (int ofs = 1; ofs < 16; ofs <<= 1) {
                int t = __shfl_up(wincl, ofs);
                if (lane >= ofs) wincl += t;
            }
            if (lane < 16) woff[lane] = wincl - ws;
            if (lane == 15) s_bt = wincl;
        }
        __syncthreads();
        int excl = s_carry + woff[wid] + incl - v;
        if (i < N) { off[i] = excl; cursor[i] = excl; }
        __syncthreads();
        if (threadIdx.x == 0) s_carry += s_bt;
        __syncthreads();
    }
    if (threadIdx.x == 0) off[N] = s_carry;
}

__global__ __launch_bounds__(256) void fill_kernel(const int* __restrict__ dst,
                                                   int* __restrict__ cursor,
                                                   int* __restrict__ perm, int E) {
    int e = blockIdx.x * blockDim.x + threadIdx.x;
    if (e < E) {
        int pos = atomicAdd(&cursor[dst[e]], 1);
        perm[pos] = e;
    }
}

// ==================== bf16 MFMA GEMM + fused asrc/adst epilogue ====================
// C16[M,256] = bf16(A16[M,K] * Bt16^T); each 64-col block == one head h=col0>>6:
// asrc[row*4+h] = sum_c acc*a_src, reduced across the 16-lane quad. [verified C/D map:
// col=lane&15, row=quad*4+reg]
__global__ __launch_bounds__(256) void gemm_bf16(const unsigned short* __restrict__ A16,
                                                 const unsigned short* __restrict__ Bt16,
                                                 unsigned short* __restrict__ C16,
                                                 const float* __restrict__ a_src,
                                                 const float* __restrict__ a_dst,
                                                 float* __restrict__ asrc,
                                                 float* __restrict__ adst,
                                                 int M, int K) {
    __shared__ unsigned short As[128][40];
    __shared__ unsigned short Bs[64][40];
    const int tid = threadIdx.x;
    const int w = tid >> 6, l = tid & 63;
    const int quad = l >> 4, m16 = l & 15;
    const int row0 = blockIdx.y * 128, col0 = blockIdx.x * 64;

    f32x4 acc[2][4] = {};

    const int a_r = tid >> 1;
    const int a_k = (tid & 1) * 16;
    const int b_n = tid >> 2;
    const int b_k = (tid & 3) * 8;

    for (int k0 = 0; k0 < K; k0 += 32) {
        int gr = row0 + a_r; if (gr > M - 1) gr = M - 1;
        const unsigned short* ap = A16 + (size_t)gr * K + k0 + a_k;
        *(us8*)&As[a_r][a_k]     = *(const us8*)ap;
        *(us8*)&As[a_r][a_k + 8] = *(const us8*)(ap + 8);
        *(us8*)&Bs[b_n][b_k] = *(const us8*)(Bt16 + (size_t)(col0 + b_n) * K + k0 + b_k);
        __syncthreads();

        s16x8 af[2], bfr[4];
#pragma unroll
        for (int mt = 0; mt < 2; ++mt)
            af[mt] = *(const s16x8*)&As[w * 32 + mt * 16 + m16][quad * 8];
#pragma unroll
        for (int nt = 0; nt < 4; ++nt)
            bfr[nt] = *(const s16x8*)&Bs[nt * 16 + m16][quad * 8];
#pragma unroll
        for (int mt = 0; mt < 2; ++mt)
#pragma unroll
            for (int nt = 0; nt < 4; ++nt)
                acc[mt][nt] = __builtin_amdgcn_mfma_f32_16x16x32_bf16(af[mt], bfr[nt], acc[mt][nt], 0, 0, 0);
        __syncthreads();
    }

    const int h = col0 >> 6;
    // per-lane a_src/a_dst weights for its 4 col positions
    float was[4], wad[4];
#pragma unroll
    for (int nt = 0; nt < 4; ++nt) {
        int c = nt * 16 + m16;
        was[nt] = a_src[h * 64 + c];
        wad[nt] = a_dst[h * 64 + c];
    }

#pragma unroll
    for (int mt = 0; mt < 2; ++mt)
#pragma unroll
        for (int i = 0; i < 4; ++i) {
            int row = row0 + w * 32 + mt * 16 + quad * 4 + i;
            float ps = 0.f, pd = 0.f;
#pragma unroll
            for (int nt = 0; nt < 4; ++nt) {
                float v = acc[mt][nt][i];
                ps += v * was[nt];
                pd += v * wad[nt];
            }
#pragma unroll
            for (int ofs = 1; ofs < 16; ofs <<= 1) {
                ps += __shfl_xor(ps, ofs);
                pd += __shfl_xor(pd, ofs);
            }
            if (m16 == 0 && row < M) {
                asrc[(size_t)row * 4 + h] = ps;
                adst[(size_t)row * 4 + h] = pd;
            }
        }

#pragma unroll
    for (int mt = 0; mt < 2; ++mt)
#pragma unroll
        for (int nt = 0; nt < 4; ++nt) {
            int col = col0 + nt * 16 + m16;
#pragma unroll
            for (int i = 0; i < 4; ++i) {
                int row = row0 + w * 32 + mt * 16 + quad * 4 + i;
                if (row < M) C16[(size_t)row * 256 + col] = f2bf(acc[mt][nt][i]);
            }
        }
}

// ==================== fused per-node softmax-reduce + aggregation ====================
// Writes amax/rdenom per node (coalesced); NO w scatter. Phase 4 aggregates from LDS.
__global__ __launch_bounds__(256) void node_fused(const int* __restrict__ perm,
                                                  const int* __restrict__ off,
                                                  const int* __restrict__ src,
                                                  const float* __restrict__ edge_attr,
                                                  const float* __restrict__ edge_atten,
                                                  const float* __restrict__ asrc,
                                                  const float* __restrict__ adst,
                                                  const float* __restrict__ ce,
                                                  const unsigned short* __restrict__ xh16,
                                                  const float* __restrict__ bias,
                                                  float* __restrict__ amax,
                                                  float* __restrict__ rdenom,
                                                  float* __restrict__ houtf,           // nullable
                                                  unsigned short* __restrict__ hout16, // nullable
                                                  int N) {
    __shared__ float s_al[4][CAP * 4];
    __shared__ float s_att[4][CAP];
    __shared__ int s_src[4][CAP];
    const int wid = threadIdx.x >> 6;
    const int n = blockIdx.x * 4 + wid;
    if (n >= N) return;
    const int lane = threadIdx.x & 63;
    float* al = s_al[wid];
    float* atb = s_att[wid];
    int* sv = s_src[wid];
    const int o0 = off[n], o1 = off[n + 1];
    const int deg = o1 - o0;

    const float4 c4 = *(const float4*)ce;
    const float4 ad4 = *(const float4*)(adst + (size_t)n * 4);

    // phase 1: raw alpha (leakyrelu) per edge -> LDS, running max
    float4 mx = make_float4(-3.4e38f, -3.4e38f, -3.4e38f, -3.4e38f);
    for (int idx = lane; idx < deg; idx += 64) {
        int e = perm[o0 + idx];
        int s = src[e];
        float ea = edge_attr[e];
        float4 as4 = *(const float4*)(asrc + (size_t)s * 4);
        float4 a;
        a.x = as4.x + ad4.x + ea * c4.x;
        a.y = as4.y + ad4.y + ea * c4.y;
        a.z = as4.z + ad4.z + ea * c4.z;
        a.w = as4.w + ad4.w + ea * c4.w;
        a.x = a.x > 0.f ? a.x : NEG_SLOPE * a.x;
        a.y = a.y > 0.f ? a.y : NEG_SLOPE * a.y;
        a.z = a.z > 0.f ? a.z : NEG_SLOPE * a.z;
        a.w = a.w > 0.f ? a.w : NEG_SLOPE * a.w;
        if (idx < CAP) {
            sv[idx] = s;
            atb[idx] = edge_atten[e];
            *(float4*)&al[idx * 4] = a;
        }
        mx.x = fmaxf(mx.x, a.x);
        mx.y = fmaxf(mx.y, a.y);
        mx.z = fmaxf(mx.z, a.z);
        mx.w = fmaxf(mx.w, a.w);
    }
#pragma unroll
    for (int ofs = 1; ofs < 64; ofs <<= 1) {
        mx.x = fmaxf(mx.x, __shfl_xor(mx.x, ofs));
        mx.y = fmaxf(mx.y, __shfl_xor(mx.y, ofs));
        mx.z = fmaxf(mx.z, __shfl_xor(mx.z, ofs));
        mx.w = fmaxf(mx.w, __shfl_xor(mx.w, ofs));
    }

    // phase 2: exp (in LDS; recompute for spill) + sum
    float4 sm = make_float4(0.f, 0.f, 0.f, 0.f);
    for (int idx = lane; idx < deg; idx += 64) {
        float4 a;
        if (idx < CAP) {
            a = *(const float4*)&al[idx * 4];
        } else {  // rare spill: recompute
            int e = perm[o0 + idx];
            int s = src[e];
            float ea = edge_attr[e];
            float4 as4 = *(const float4*)(asrc + (size_t)s * 4);
            a.x = as4.x + ad4.x + ea * c4.x;
            a.y = as4.y + ad4.y + ea * c4.y;
            a.z = as4.z + ad4.z + ea * c4.z;
            a.w = as4.w + ad4.w + ea * c4.w;
            a.x = a.x > 0.f ? a.x : NEG_SLOPE * a.x;
            a.y = a.y > 0.f ? a.y : NEG_SLOPE * a.y;
            a.z = a.z > 0.f ? a.z : NEG_SLOPE * a.z;
            a.w = a.w > 0.f ? a.w : NEG_SLOPE * a.w;
        }
        a.x = __expf(a.x - mx.x);
        a.y = __expf(a.y - mx.y);
        a.z = __expf(a.z - mx.z);
        a.w = __expf(a.w - mx.w);
        if (idx < CAP) *(float4*)&al[idx * 4] = a;
        sm.x += a.x; sm.y += a.y; sm.z += a.z; sm.w += a.w;
    }
#pragma unroll
    for (int ofs = 1; ofs < 64; ofs <<= 1) {
        sm.x += __shfl_xor(sm.x, ofs);
        sm.y += __shfl_xor(sm.y, ofs);
        sm.z += __shfl_xor(sm.z, ofs);
        sm.w += __shfl_xor(sm.w, ofs);
    }
    float4 rc;
    rc.x = 1.f / (sm.x + 1e-16f);
    rc.y = 1.f / (sm.y + 1e-16f);
    rc.z = 1.f / (sm.z + 1e-16f);
    rc.w = 1.f / (sm.w + 1e-16f);
    if (lane == 0) {
        *(float4*)(amax + (size_t)n * 4) = mx;
        *(float4*)(rdenom + (size_t)n * 4) = rc;
    }

    // phase 3 (LDS only): al <- al * rc * att
    for (int idx = lane; idx < deg && idx < CAP; idx += 64) {
        float att = atb[idx];
        float4 ex = *(const float4*)&al[idx * 4];
        ex.x *= rc.x * att;
        ex.y *= rc.y * att;
        ex.z *= rc.z * att;
        ex.w *= rc.w * att;
        *(float4*)&al[idx * 4] = ex;
    }

    // phase 4: aggregation, lane = channel (4 ch/lane), bf16 gather, unroll x4
    const int hh = lane >> 4;
    float4 acc = *(const float4*)(bias + lane * 4);
    const int kmax = deg < CAP ? deg : CAP;
    int k = 0;
    for (; k + 4 <= kmax; k += 4) {
        int s0 = sv[k], s1 = sv[k + 1], s2 = sv[k + 2], s3 = sv[k + 3];
        float c0 = al[(k + 0) * 4 + hh];
        float c1 = al[(k + 1) * 4 + hh];
        float c2 = al[(k + 2) * 4 + hh];
        float c3 = al[(k + 3) * 4 + hh];
        ushort4 u0 = *((const ushort4*)(xh16 + (size_t)s0 * 256) + lane);
        ushort4 u1 = *((const ushort4*)(xh16 + (size_t)s1 * 256) + lane);
        ushort4 u2 = *((const ushort4*)(xh16 + (size_t)s2 * 256) + lane);
        ushort4 u3 = *((const ushort4*)(xh16 + (size_t)s3 * 256) + lane);
        acc.x += bf2f(u0.x) * c0; acc.y += bf2f(u0.y) * c0; acc.z += bf2f(u0.z) * c0; acc.w += bf2f(u0.w) * c0;
        acc.x += bf2f(u1.x) * c1; acc.y += bf2f(u1.y) * c1; acc.z += bf2f(u1.z) * c1; acc.w += bf2f(u1.w) * c1;
        acc.x += bf2f(u2.x) * c2; acc.y += bf2f(u2.y) * c2; acc.z += bf2f(u2.z) * c2; acc.w += bf2f(u2.w) * c2;
        acc.x += bf2f(u3.x) * c3; acc.y += bf2f(u3.y) * c3; acc.z += bf2f(u3.z) * c3; acc.w += bf2f(u3.w) * c3;
    }
    for (; k < kmax; ++k) {
        int s = sv[k];
        float sc = al[k * 4 + hh];
        ushort4 uv = *((const ushort4*)(xh16 + (size_t)s * 256) + lane);
        acc.x += bf2f(uv.x) * sc; acc.y += bf2f(uv.y) * sc;
        acc.z += bf2f(uv.z) * sc; acc.w += bf2f(uv.w) * sc;
    }
    for (k = CAP; k < deg; ++k) {   // rare spill: recompute weight for head hh
        int e = perm[o0 + k];
        int s = src[e];
        float a = asrc[(size_t)s * 4 + hh] + ((const float*)&ad4)[hh]
                + edge_attr[e] * ((const float*)&c4)[hh];
        a = a > 0.f ? a : NEG_SLOPE * a;
        float sc = __expf(a - ((const float*)&mx)[hh]) * ((const float*)&rc)[hh] * edge_atten[e];
        ushort4 uv = *((const ushort4*)(xh16 + (size_t)s * 256) + lane);
        acc.x += bf2f(uv.x) * sc; acc.y += bf2f(uv.y) * sc;
        acc.z += bf2f(uv.z) * sc; acc.w += bf2f(uv.w) * sc;
    }
    if (houtf)  *(float4*)(houtf + (size_t)n * 256 + lane * 4) = acc;
    if (hout16) {
        ushort4 u = make_ushort4(f2bf(acc.x), f2bf(acc.y), f2bf(acc.z), f2bf(acc.w));
        *((ushort4*)(hout16 + (size_t)n * 256) + lane) = u;
    }
}

// ==================== write_w: edge-parallel, fully coalesced w output ====================
__global__ __launch_bounds__(256) void write_w(const int* __restrict__ src,
                                               const int* __restrict__ dst,
                                               const float* __restrict__ edge_attr,
                                               const float* __restrict__ asrc,
                                               const float* __restrict__ adst,
                                               const float* __restrict__ amax,
                                               const float* __restrict__ rdenom,
                                               const float* __restrict__ ce,
                                               float* __restrict__ w, int E) {
    int e = blockIdx.x * blockDim.x + threadIdx.x;
    if (e >= E) return;
    int s = src[e], d = dst[e];
    float ea = edge_attr[e];
    float4 as4 = *(const float4*)(asrc + (size_t)s * 4);
    float4 ad4 = *(const float4*)(adst + (size_t)d * 4);
    float4 mx4 = *(const float4*)(amax + (size_t)d * 4);
    float4 rc4 = *(const float4*)(rdenom + (size_t)d * 4);
    float4 c4 = *(const float4*)ce;
    float4 a;
    a.x = as4.x + ad4.x + ea * c4.x;
    a.y = as4.y + ad4.y + ea * c4.y;
    a.z = as4.z + ad4.z + ea * c4.z;
    a.w = as4.w + ad4.w + ea * c4.w;
    a.x = a.x > 0.f ? a.x : NEG_SLOPE * a.x;
    a.y = a.y > 0.f ? a.y : NEG_SLOPE * a.y;
    a.z = a.z > 0.f ? a.z : NEG_SLOPE * a.z;
    a.w = a.w > 0.f ? a.w : NEG_SLOPE * a.w;
    float4 v;
    v.x = __expf(a.x - mx4.x) * rc4.x;
    v.y = __expf(a.y - mx4.y) * rc4.y;
    v.z = __expf(a.z - mx4.z) * rc4.z;
    v.w = __expf(a.w - mx4.w) * rc4.w;
    *(float4*)(w + (size_t)e * 4) = v;
}

extern "C" void kernel_launch(void* const* d_in, const int* in_sizes, int n_in,
                              void* d_out, int out_size, void* d_ws, size_t ws_size,
                              hipStream_t stream) {
    const float* x          = (const float*)d_in[0];
    const int*   ei         = (const int*)d_in[1];
    const float* edge_attr  = (const float*)d_in[3];
    const float* edge_atten = (const float*)d_in[4];
    const float* W1     = (const float*)d_in[5];
    const float* a_src1 = (const float*)d_in[6];
    const float* a_dst1 = (const float*)d_in[7];
    const float* W_e1   = (const float*)d_in[8];
    const float* a_e1   = (const float*)d_in[9];
    const float* b1     = (const float*)d_in[10];
    const float* W2     = (const float*)d_in[11];
    const float* a_src2 = (const float*)d_in[12];
    const float* a_dst2 = (const float*)d_in[13];
    const float* W_e2   = (const float*)d_in[14];
    const float* a_e2   = (const float*)d_in[15];
    const float* b2     = (const float*)d_in[16];

    const int N = in_sizes[0] / 128;   // 20000
    const int E = in_sizes[1] / 2;     // 640000
    const int* srcp = ei;
    const int* dstp = ei + E;

    char* ws = (char*)d_ws;
    unsigned short* x16   = (unsigned short*)ws;  ws += (size_t)N * 128 * 2;
    unsigned short* xh16  = (unsigned short*)ws;  ws += (size_t)N * 256 * 2;
    unsigned short* h116  = (unsigned short*)ws;  ws += (size_t)N * 256 * 2;
    unsigned short* Wt1   = (unsigned short*)ws;  ws += (size_t)256 * 128 * 2;
    unsigned short* Wt2   = (unsigned short*)ws;  ws += (size_t)256 * 256 * 2;
    float* asrc   = (float*)ws;                   ws += (size_t)N * 4 * 4;
    float* adst   = (float*)ws;                   ws += (size_t)N * 4 * 4;
    float* amax   = (float*)ws;                   ws += (size_t)N * 4 * 4;
    float* rdenom = (float*)ws;                   ws += (size_t)N * 4 * 4;
    float* ce     = (float*)ws;                   ws += 32;   // ce1[4], ce2[4]
    int* deg    = (int*)ws;                       ws += (size_t)N * 4;
    int* off    = (int*)ws;                       ws += (size_t)(N + 1) * 4;
    int* cursor = (int*)ws;                       ws += (size_t)N * 4;
    int* perm   = (int*)ws;                       ws += (size_t)E * 4;

    float* hout2 = (float*)d_out;                 // N*256
    float* w1    = hout2 + (size_t)N * 256;       // E*4
    float* w2    = w1 + (size_t)E * 4;            // E*4

    dim3 gemm_grid(4, (N + 127) / 128);
    int eb = (E + 255) / 256;
    int gb = (N + 3) / 4;

    // ---------------- prep + CSR build ----------------
    prep_kernel<<<512, 256, 0, stream>>>(x, W1, W2, W_e1, a_e1, W_e2, a_e2,
                                         x16, Wt1, Wt2, deg, ce, N);
    hist_kernel<<<eb, 256, 0, stream>>>(dstp, deg, E);
    scan_kernel<<<1, 1024, 0, stream>>>(deg, off, cursor, N);
    fill_kernel<<<eb, 256, 0, stream>>>(dstp, cursor, perm, E);

    // ---------------- layer 1 ----------------
    gemm_bf16<<<gemm_grid, 256, 0, stream>>>(x16, Wt1, xh16, a_src1, a_dst1,
                                             asrc, adst, N, 128);
    node_fused<<<gb, 256, 0, stream>>>(perm, off, srcp, edge_attr, edge_atten,
                                       asrc, adst, ce, xh16, b1, amax, rdenom,
                                       (float*)nullptr, h116, N);
    write_w<<<eb, 256, 0, stream>>>(srcp, dstp, edge_attr, asrc, adst,
                                    amax, rdenom, ce, w1, E);

    // ---------------- layer 2 ----------------
    gemm_bf16<<<gemm_grid, 256, 0, stream>>>(h116, Wt2, xh16, a_src2, a_dst2,
                                             asrc, adst, N, 256);
    node_fused<<<gb, 256, 0, stream>>>(perm, off, srcp, edge_attr, edge_atten,
                                       asrc, adst, ce + 4, xh16, b2, amax, rdenom,
                                       hout2, (unsigned short*)nullptr, N);
    write_w<<<eb, 256, 0, stream>>>(srcp, dstp, edge_attr, asrc, adst,
                                    amax, rdenom, ce + 4, w2, E);
}

// Round 8
// 321.615 us; speedup vs baseline: 1.2930x; 1.2930x over previous
//
#include <hip/hip_runtime.h>
#include <math.h>

#define NEG_SLOPE 0.2f
#define CAP 128   // max in-edges/node in LDS; deg~Binom(640K,1/20K) mean 32 → ample

typedef short s16x8 __attribute__((ext_vector_type(8)));
typedef unsigned short us8 __attribute__((ext_vector_type(8)));
typedef float f32x4 __attribute__((ext_vector_type(4)));

__device__ __forceinline__ unsigned short f2bf(float f) {
    unsigned int u = __float_as_uint(f);
    return (unsigned short)((u + 0x7FFFu + ((u >> 16) & 1u)) >> 16);
}
__device__ __forceinline__ float bf2f(unsigned short s) {
    return __uint_as_float(((unsigned int)s) << 16);
}

// ==================== prep: W1/W2 transpose->bf16, deg=0, ce1/ce2 ====================
__global__ __launch_bounds__(256) void prep_kernel(const float* __restrict__ W1,
                                                   const float* __restrict__ W2,
                                                   const float* __restrict__ W_e1,
                                                   const float* __restrict__ a_e1,
                                                   const float* __restrict__ W_e2,
                                                   const float* __restrict__ a_e2,
                                                   unsigned short* __restrict__ Wt1,
                                                   unsigned short* __restrict__ Wt2,
                                                   int* __restrict__ deg,
                                                   float* __restrict__ ce,  // [8]: ce1, ce2
                                                   int N) {
    const int gsz = gridDim.x * blockDim.x;
    int gid = blockIdx.x * blockDim.x + threadIdx.x;
    for (int i = gid; i < 128 * 256; i += gsz) {
        int k = i >> 8, n = i & 255;
        Wt1[n * 128 + k] = f2bf(W1[i]);
    }
    for (int i = gid; i < 256 * 256; i += gsz) {
        int k = i >> 8, n = i & 255;
        Wt2[n * 256 + k] = f2bf(W2[i]);
    }
    for (int i = gid; i < N; i += gsz) deg[i] = 0;
    if (blockIdx.x < 2) {
        const float* We = blockIdx.x == 0 ? W_e1 : W_e2;
        const float* ae = blockIdx.x == 0 ? a_e1 : a_e2;
        int h = threadIdx.x >> 6, c = threadIdx.x & 63;
        float p = We[h * 64 + c] * ae[h * 64 + c];
#pragma unroll
        for (int off = 32; off > 0; off >>= 1) p += __shfl_down(p, off);
        if (c == 0) ce[blockIdx.x * 4 + h] = p;
    }
}

// ==================== CSR build ====================
__global__ __launch_bounds__(256) void hist_kernel(const int* __restrict__ dst,
                                                   int* __restrict__ deg, int E) {
    int e = blockIdx.x * blockDim.x + threadIdx.x;
    if (e < E) atomicAdd(&deg[dst[e]], 1);
}

// single-block exclusive scan, 4 elems/thread, shuffle-based
__global__ __launch_bounds__(1024) void scan_kernel(const int* __restrict__ deg,
                                                    int* __restrict__ off,
                                                    int* __restrict__ cursor, int N) {
    __shared__ int wsum[16];
    __shared__ int woff[16];
    __shared__ int s_carry, s_bt;
    if (threadIdx.x == 0) s_carry = 0;
    __syncthreads();
    const int lane = threadIdx.x & 63, wid = threadIdx.x >> 6;
    for (int base = 0; base < N; base += 4096) {
        int i0 = base + (int)threadIdx.x * 4;
        int v0 = (i0 + 0 < N) ? deg[i0 + 0] : 0;
        int v1 = (i0 + 1 < N) ? deg[i0 + 1] : 0;
        int v2 = (i0 + 2 < N) ? deg[i0 + 2] : 0;
        int v3 = (i0 + 3 < N) ? deg[i0 + 3] : 0;
        int tsum = v0 + v1 + v2 + v3;
        int incl = tsum;
#pragma unroll
        for (int ofs = 1; ofs < 64; ofs <<= 1) {
            int t = __shfl_up(incl, ofs);
            if (lane >= ofs) incl += t;
        }
        if (lane == 63) wsum[wid] = incl;
        __syncthreads();
        if (wid == 0) {
            int ws = (lane < 16) ? wsum[lane] : 0;
            int wincl = ws;
#pragma unroll
            for (int ofs = 1; ofs < 16; ofs <<= 1) {
                int t = __shfl_up(wincl, ofs);
                if (lane >= ofs) wincl += t;
            }
            if (lane < 16) woff[lane] = wincl - ws;
            if (lane == 15) s_bt = wincl;
        }
        __syncthreads();
        int e0 = s_carry + woff[wid] + incl - tsum;
        int e1 = e0 + v0, e2 = e1 + v1, e3 = e2 + v2;
        if (i0 + 0 < N) { off[i0 + 0] = e0; cursor[i0 + 0] = e0; }
        if (i0 + 1 < N) { off[i0 + 1] = e1; cursor[i0 + 1] = e1; }
        if (i0 + 2 < N) { off[i0 + 2] = e2; cursor[i0 + 2] = e2; }
        if (i0 + 3 < N) { off[i0 + 3] = e3; cursor[i0 + 3] = e3; }
        __syncthreads();
        if (threadIdx.x == 0) s_carry += s_bt;
        __syncthreads();
    }
    if (threadIdx.x == 0) off[N] = s_carry;
}

// fill: bucket edges by dst, emitting packed record {src, e, attr_bits, atten_bits}
__global__ __launch_bounds__(256) void fill_kernel(const int* __restrict__ src,
                                                   const int* __restrict__ dst,
                                                   const float* __restrict__ edge_attr,
                                                   const float* __restrict__ edge_atten,
                                                   int* __restrict__ cursor,
                                                   int4* __restrict__ rec, int E) {
    int e = blockIdx.x * blockDim.x + threadIdx.x;
    if (e < E) {
        int pos = atomicAdd(&cursor[dst[e]], 1);
        rec[pos] = make_int4(src[e], e, __float_as_int(edge_attr[e]),
                             __float_as_int(edge_atten[e]));
    }
}

// ==================== bf16 MFMA GEMM + fused asrc/adst epilogue ====================
// C16[M,256] = bf16(A*Bt16^T); A from A16 (bf16) or A32 (fp32, converted in staging).
// Each 64-col block == one head h: asrc/adst reduced across the 16-lane quad.
// [verified C/D map: col=lane&15, row=quad*4+reg]
__global__ __launch_bounds__(256) void gemm_bf16(const unsigned short* __restrict__ A16,
                                                 const float* __restrict__ A32,
                                                 const unsigned short* __restrict__ Bt16,
                                                 unsigned short* __restrict__ C16,
                                                 const float* __restrict__ a_src,
                                                 const float* __restrict__ a_dst,
                                                 float* __restrict__ asrc,
                                                 float* __restrict__ adst,
                                                 int M, int K) {
    __shared__ unsigned short As[128][40];
    __shared__ unsigned short Bs[64][40];
    const int tid = threadIdx.x;
    const int w = tid >> 6, l = tid & 63;
    const int quad = l >> 4, m16 = l & 15;
    const int row0 = blockIdx.y * 128, col0 = blockIdx.x * 64;

    f32x4 acc[2][4] = {};

    const int a_r = tid >> 1;
    const int a_k = (tid & 1) * 16;
    const int b_n = tid >> 2;
    const int b_k = (tid & 3) * 8;

    for (int k0 = 0; k0 < K; k0 += 32) {
        int gr = row0 + a_r; if (gr > M - 1) gr = M - 1;
        if (A32) {
            const float* ap = A32 + (size_t)gr * K + k0 + a_k;
            float4 f0 = *(const float4*)(ap);
            float4 f1 = *(const float4*)(ap + 4);
            float4 f2 = *(const float4*)(ap + 8);
            float4 f3 = *(const float4*)(ap + 12);
            unsigned short* dst0 = &As[a_r][a_k];
            dst0[0] = f2bf(f0.x); dst0[1] = f2bf(f0.y); dst0[2] = f2bf(f0.z); dst0[3] = f2bf(f0.w);
            dst0[4] = f2bf(f1.x); dst0[5] = f2bf(f1.y); dst0[6] = f2bf(f1.z); dst0[7] = f2bf(f1.w);
            dst0[8] = f2bf(f2.x); dst0[9] = f2bf(f2.y); dst0[10] = f2bf(f2.z); dst0[11] = f2bf(f2.w);
            dst0[12] = f2bf(f3.x); dst0[13] = f2bf(f3.y); dst0[14] = f2bf(f3.z); dst0[15] = f2bf(f3.w);
        } else {
            const unsigned short* ap = A16 + (size_t)gr * K + k0 + a_k;
            *(us8*)&As[a_r][a_k]     = *(const us8*)ap;
            *(us8*)&As[a_r][a_k + 8] = *(const us8*)(ap + 8);
        }
        *(us8*)&Bs[b_n][b_k] = *(const us8*)(Bt16 + (size_t)(col0 + b_n) * K + k0 + b_k);
        __syncthreads();

        s16x8 af[2], bfr[4];
#pragma unroll
        for (int mt = 0; mt < 2; ++mt)
            af[mt] = *(const s16x8*)&As[w * 32 + mt * 16 + m16][quad * 8];
#pragma unroll
        for (int nt = 0; nt < 4; ++nt)
            bfr[nt] = *(const s16x8*)&Bs[nt * 16 + m16][quad * 8];
#pragma unroll
        for (int mt = 0; mt < 2; ++mt)
#pragma unroll
            for (int nt = 0; nt < 4; ++nt)
                acc[mt][nt] = __builtin_amdgcn_mfma_f32_16x16x32_bf16(af[mt], bfr[nt], acc[mt][nt], 0, 0, 0);
        __syncthreads();
    }

    const int h = col0 >> 6;
    float was[4], wad[4];
#pragma unroll
    for (int nt = 0; nt < 4; ++nt) {
        int c = nt * 16 + m16;
        was[nt] = a_src[h * 64 + c];
        wad[nt] = a_dst[h * 64 + c];
    }

#pragma unroll
    for (int mt = 0; mt < 2; ++mt)
#pragma unroll
        for (int i = 0; i < 4; ++i) {
            int row = row0 + w * 32 + mt * 16 + quad * 4 + i;
            float ps = 0.f, pd = 0.f;
#pragma unroll
            for (int nt = 0; nt < 4; ++nt) {
                float v = acc[mt][nt][i];
                ps += v * was[nt];
                pd += v * wad[nt];
            }
#pragma unroll
            for (int ofs = 1; ofs < 16; ofs <<= 1) {
                ps += __shfl_xor(ps, ofs);
                pd += __shfl_xor(pd, ofs);
            }
            if (m16 == 0 && row < M) {
                asrc[(size_t)row * 4 + h] = ps;
                adst[(size_t)row * 4 + h] = pd;
            }
        }

#pragma unroll
    for (int mt = 0; mt < 2; ++mt)
#pragma unroll
        for (int nt = 0; nt < 4; ++nt) {
            int col = col0 + nt * 16 + m16;
#pragma unroll
            for (int i = 0; i < 4; ++i) {
                int row = row0 + w * 32 + mt * 16 + quad * 4 + i;
                if (row < M) C16[(size_t)row * 256 + col] = f2bf(acc[mt][nt][i]);
            }
        }
}

// ==================== fused per-node softmax + aggregation (R6 structure + rec) ====================
__global__ __launch_bounds__(256) void node_fused(const int4* __restrict__ rec,
                                                  const int* __restrict__ off,
                                                  const float* __restrict__ asrc,
                                                  const float* __restrict__ adst,
                                                  const float* __restrict__ ce,
                                                  const unsigned short* __restrict__ xh16,
                                                  const float* __restrict__ bias,
                                                  float* __restrict__ w,
                                                  float* __restrict__ houtf,           // nullable
                                                  unsigned short* __restrict__ hout16, // nullable
                                                  int N) {
    __shared__ float s_al[4][CAP * 4];
    __shared__ int s_src[4][CAP];
    const int wid = threadIdx.x >> 6;
    const int n = blockIdx.x * 4 + wid;
    if (n >= N) return;
    const int lane = threadIdx.x & 63;
    float* al = s_al[wid];
    int* sv = s_src[wid];
    const int o0 = off[n], o1 = off[n + 1];
    const int deg = o1 - o0;

    const float4 c4 = *(const float4*)ce;
    const float4 ad4 = *(const float4*)(adst + (size_t)n * 4);

    // phase 1: raw alpha (leakyrelu) per edge, running max; edge data coalesced via rec
    float4 mx = make_float4(-3.4e38f, -3.4e38f, -3.4e38f, -3.4e38f);
    for (int idx = lane; idx < deg; idx += 64) {
        int4 r = rec[o0 + idx];
        int s = r.x;
        float ea = __int_as_float(r.z);
        float4 as4 = *(const float4*)(asrc + (size_t)s * 4);
        float4 a;
        a.x = as4.x + ad4.x + ea * c4.x;
        a.y = as4.y + ad4.y + ea * c4.y;
        a.z = as4.z + ad4.z + ea * c4.z;
        a.w = as4.w + ad4.w + ea * c4.w;
        a.x = a.x > 0.f ? a.x : NEG_SLOPE * a.x;
        a.y = a.y > 0.f ? a.y : NEG_SLOPE * a.y;
        a.z = a.z > 0.f ? a.z : NEG_SLOPE * a.z;
        a.w = a.w > 0.f ? a.w : NEG_SLOPE * a.w;
        if (idx < CAP) {
            sv[idx] = s;
            *(float4*)&al[idx * 4] = a;
        } else {
            *(float4*)(w + (size_t)r.y * 4) = a;  // rare spill
        }
        mx.x = fmaxf(mx.x, a.x);
        mx.y = fmaxf(mx.y, a.y);
        mx.z = fmaxf(mx.z, a.z);
        mx.w = fmaxf(mx.w, a.w);
    }
#pragma unroll
    for (int ofs = 1; ofs < 64; ofs <<= 1) {
        mx.x = fmaxf(mx.x, __shfl_xor(mx.x, ofs));
        mx.y = fmaxf(mx.y, __shfl_xor(mx.y, ofs));
        mx.z = fmaxf(mx.z, __shfl_xor(mx.z, ofs));
        mx.w = fmaxf(mx.w, __shfl_xor(mx.w, ofs));
    }

    // phase 2: exp + sum
    float4 sm = make_float4(0.f, 0.f, 0.f, 0.f);
    for (int idx = lane; idx < deg; idx += 64) {
        float4 a;
        int espill = -1;
        if (idx < CAP) a = *(const float4*)&al[idx * 4];
        else { espill = rec[o0 + idx].y; a = *(const float4*)(w + (size_t)espill * 4); }
        a.x = __expf(a.x - mx.x);
        a.y = __expf(a.y - mx.y);
        a.z = __expf(a.z - mx.z);
        a.w = __expf(a.w - mx.w);
        if (idx < CAP) *(float4*)&al[idx * 4] = a;
        else *(float4*)(w + (size_t)espill * 4) = a;
        sm.x += a.x; sm.y += a.y; sm.z += a.z; sm.w += a.w;
    }
#pragma unroll
    for (int ofs = 1; ofs < 64; ofs <<= 1) {
        sm.x += __shfl_xor(sm.x, ofs);
        sm.y += __shfl_xor(sm.y, ofs);
        sm.z += __shfl_xor(sm.z, ofs);
        sm.w += __shfl_xor(sm.w, ofs);
    }
    float4 rc;
    rc.x = 1.f / (sm.x + 1e-16f);
    rc.y = 1.f / (sm.y + 1e-16f);
    rc.z = 1.f / (sm.z + 1e-16f);
    rc.w = 1.f / (sm.w + 1e-16f);

    // phase 3: normalize, write w (scatter, float4/edge), fold edge_atten into LDS copy
    for (int idx = lane; idx < deg; idx += 64) {
        int4 r = rec[o0 + idx];
        float4 ex = (idx < CAP) ? *(const float4*)&al[idx * 4]
                                : *(const float4*)(w + (size_t)r.y * 4);
        float4 aln;
        aln.x = ex.x * rc.x;
        aln.y = ex.y * rc.y;
        aln.z = ex.z * rc.z;
        aln.w = ex.w * rc.w;
        *(float4*)(w + (size_t)r.y * 4) = aln;
        if (idx < CAP) {
            float att = __int_as_float(r.w);
            aln.x *= att; aln.y *= att; aln.z *= att; aln.w *= att;
            *(float4*)&al[idx * 4] = aln;
        }
    }

    // phase 4: aggregation, lane = channel (4 ch/lane), bf16 gather, unroll x4
    const int hh = lane >> 4;
    float4 acc = *(const float4*)(bias + lane * 4);
    const int kmax = deg < CAP ? deg : CAP;
    int k = 0;
    for (; k + 4 <= kmax; k += 4) {
        int s0 = sv[k], s1 = sv[k + 1], s2 = sv[k + 2], s3 = sv[k + 3];
        float c0 = al[(k + 0) * 4 + hh];
        float c1 = al[(k + 1) * 4 + hh];
        float c2 = al[(k + 2) * 4 + hh];
        float c3 = al[(k + 3) * 4 + hh];
        ushort4 u0 = *((const ushort4*)(xh16 + (size_t)s0 * 256) + lane);
        ushort4 u1 = *((const ushort4*)(xh16 + (size_t)s1 * 256) + lane);
        ushort4 u2 = *((const ushort4*)(xh16 + (size_t)s2 * 256) + lane);
        ushort4 u3 = *((const ushort4*)(xh16 + (size_t)s3 * 256) + lane);
        acc.x += bf2f(u0.x) * c0; acc.y += bf2f(u0.y) * c0; acc.z += bf2f(u0.z) * c0; acc.w += bf2f(u0.w) * c0;
        acc.x += bf2f(u1.x) * c1; acc.y += bf2f(u1.y) * c1; acc.z += bf2f(u1.z) * c1; acc.w += bf2f(u1.w) * c1;
        acc.x += bf2f(u2.x) * c2; acc.y += bf2f(u2.y) * c2; acc.z += bf2f(u2.z) * c2; acc.w += bf2f(u2.w) * c2;
        acc.x += bf2f(u3.x) * c3; acc.y += bf2f(u3.y) * c3; acc.z += bf2f(u3.z) * c3; acc.w += bf2f(u3.w) * c3;
    }
    for (; k < kmax; ++k) {
        int s = sv[k];
        float sc = al[k * 4 + hh];
        ushort4 uv = *((const ushort4*)(xh16 + (size_t)s * 256) + lane);
        acc.x += bf2f(uv.x) * sc; acc.y += bf2f(uv.y) * sc;
        acc.z += bf2f(uv.z) * sc; acc.w += bf2f(uv.w) * sc;
    }
    for (k = CAP; k < deg; ++k) {   // rare spill path
        int4 r = rec[o0 + k];
        float sc = w[(size_t)r.y * 4 + hh] * __int_as_float(r.w);
        ushort4 uv = *((const ushort4*)(xh16 + (size_t)r.x * 256) + lane);
        acc.x += bf2f(uv.x) * sc; acc.y += bf2f(uv.y) * sc;
        acc.z += bf2f(uv.z) * sc; acc.w += bf2f(uv.w) * sc;
    }
    if (houtf)  *(float4*)(houtf + (size_t)n * 256 + lane * 4) = acc;
    if (hout16) {
        ushort4 u = make_ushort4(f2bf(acc.x), f2bf(acc.y), f2bf(acc.z), f2bf(acc.w));
        *((ushort4*)(hout16 + (size_t)n * 256) + lane) = u;
    }
}

extern "C" void kernel_launch(void* const* d_in, const int* in_sizes, int n_in,
                              void* d_out, int out_size, void* d_ws, size_t ws_size,
                              hipStream_t stream) {
    const float* x          = (const float*)d_in[0];
    const int*   ei         = (const int*)d_in[1];
    const float* edge_attr  = (const float*)d_in[3];
    const float* edge_atten = (const float*)d_in[4];
    const float* W1     = (const float*)d_in[5];
    const float* a_src1 = (const float*)d_in[6];
    const float* a_dst1 = (const float*)d_in[7];
    const float* W_e1   = (const float*)d_in[8];
    const float* a_e1   = (const float*)d_in[9];
    const float* b1     = (const float*)d_in[10];
    const float* W2     = (const float*)d_in[11];
    const float* a_src2 = (const float*)d_in[12];
    const float* a_dst2 = (const float*)d_in[13];
    const float* W_e2   = (const float*)d_in[14];
    const float* a_e2   = (const float*)d_in[15];
    const float* b2     = (const float*)d_in[16];

    const int N = in_sizes[0] / 128;   // 20000
    const int E = in_sizes[1] / 2;     // 640000
    const int* srcp = ei;
    const int* dstp = ei + E;

    char* ws = (char*)d_ws;
    int4* rec             = (int4*)ws;            ws += (size_t)E * 16;       // 16B-aligned first
    unsigned short* xh16  = (unsigned short*)ws;  ws += (size_t)N * 256 * 2;
    unsigned short* h116  = (unsigned short*)ws;  ws += (size_t)N * 256 * 2;
    unsigned short* Wt1   = (unsigned short*)ws;  ws += (size_t)256 * 128 * 2;
    unsigned short* Wt2   = (unsigned short*)ws;  ws += (size_t)256 * 256 * 2;
    float* asrc   = (float*)ws;                   ws += (size_t)N * 4 * 4;
    float* adst   = (float*)ws;                   ws += (size_t)N * 4 * 4;
    float* ce     = (float*)ws;                   ws += 32;   // ce1[4], ce2[4]
    int* deg    = (int*)ws;                       ws += (size_t)N * 4;
    int* off    = (int*)ws;                       ws += (size_t)(N + 1) * 4;
    int* cursor = (int*)ws;                       ws += (size_t)N * 4;

    float* hout2 = (float*)d_out;                 // N*256
    float* w1    = hout2 + (size_t)N * 256;       // E*4
    float* w2    = w1 + (size_t)E * 4;            // E*4

    dim3 gemm_grid(4, (N + 127) / 128);
    int eb = (E + 255) / 256;
    int gb = (N + 3) / 4;

    // ---------------- prep + CSR build ----------------
    prep_kernel<<<256, 256, 0, stream>>>(W1, W2, W_e1, a_e1, W_e2, a_e2,
                                         Wt1, Wt2, deg, ce, N);
    hist_kernel<<<eb, 256, 0, stream>>>(dstp, deg, E);
    scan_kernel<<<1, 1024, 0, stream>>>(deg, off, cursor, N);
    fill_kernel<<<eb, 256, 0, stream>>>(srcp, dstp, edge_attr, edge_atten,
                                        cursor, rec, E);

    // ---------------- layer 1 (A = fp32 x, converted in staging) ----------------
    gemm_bf16<<<gemm_grid, 256, 0, stream>>>((const unsigned short*)nullptr, x, Wt1,
                                             xh16, a_src1, a_dst1, asrc, adst, N, 128);
    node_fused<<<gb, 256, 0, stream>>>(rec, off, asrc, adst, ce, xh16, b1, w1,
                                       (float*)nullptr, h116, N);

    // ---------------- layer 2 ----------------
    gemm_bf16<<<gemm_grid, 256, 0, stream>>>(h116, (const float*)nullptr, Wt2,
                                             xh16, a_src2, a_dst2, asrc, adst, N, 256);
    node_fused<<<gb, 256, 0, stream>>>(rec, off, asrc, adst, ce + 4, xh16, b2, w2,
                                       hout2, (unsigned short*)nullptr, N);
}